// Round 2
// baseline (655.049 us; speedup 1.0000x reference)
//
#include <hip/hip_runtime.h>

// Problem constants (from reference): B=16, F=257, M=6, T=1000, N_ITER=2
#define BQ 16
#define FQ 257
#define MQ 6
#define TQ 1000
#define BFQ (BQ * FQ)            // 4112 independent (b,f) problems
#define FMTQ (FQ * MQ * TQ)      // 1,542,000  (divisor for per-batch scale mean)

// Hermitian pair indexing: 21 (m<=n) real parts, 15 (m<n) imag parts
__device__ __host__ constexpr int SIDX(int m, int n) { return m * 6 - m * (m + 1) / 2 + n; }
__device__ __host__ constexpr int AIDX(int m, int n) { return m * 5 - m * (m + 1) / 2 + n - 1; }

// ---------------------------------------------------------------------------
// K0: zero the 32 scale accumulators (S1[16], S2[16] contiguous)
// ---------------------------------------------------------------------------
__global__ void k_zero(float* __restrict__ S) {
    if (threadIdx.x < 32) S[threadIdx.x] = 0.0f;
}

// ---------------------------------------------------------------------------
// K1: per (b,f):
//   V[k][m][n] = (1/T) sum_t r[k,t] * x[m,t] * conj(x[n,t])  + eps on diagonal
//   C[m][n]    =        sum_t x[m,t] * conj(x[n,t])   (for trace-based scale)
// One 64-lane wave per (b,f); lane strides t; Hermitian-compact accumulators
// in registers; butterfly wave-reduce; lane 0 writes full complex matrices.
// ---------------------------------------------------------------------------
__global__ __launch_bounds__(64) void k_stats(
    const float* __restrict__ r, const float* __restrict__ xre,
    const float* __restrict__ xim, float* __restrict__ V, float* __restrict__ Cw)
{
    const int bf   = blockIdx.x;
    const int lane = threadIdx.x;
    const float* rp  = r   + (size_t)bf * MQ * TQ;
    const float* xrp = xre + (size_t)bf * MQ * TQ;
    const float* xip = xim + (size_t)bf * MQ * TQ;

    float Vre[6][21], Vim[6][15], Cre[21], Cim[15];
#pragma unroll
    for (int k = 0; k < 6; k++) {
#pragma unroll
        for (int p = 0; p < 21; p++) Vre[k][p] = 0.0f;
#pragma unroll
        for (int p = 0; p < 15; p++) Vim[k][p] = 0.0f;
    }
#pragma unroll
    for (int p = 0; p < 21; p++) Cre[p] = 0.0f;
#pragma unroll
    for (int p = 0; p < 15; p++) Cim[p] = 0.0f;

#pragma unroll 2
    for (int t = lane; t < TQ; t += 64) {
        float rr[6], ar[6], ai[6];
#pragma unroll
        for (int k = 0; k < 6; k++) rr[k] = rp[k * TQ + t];
#pragma unroll
        for (int m = 0; m < 6; m++) { ar[m] = xrp[m * TQ + t]; ai[m] = xip[m * TQ + t]; }

#pragma unroll
        for (int m = 0; m < 6; m++) {
            // diagonal pair: p = |x[m]|^2 (imag exactly 0)
            {
                const float pr = ar[m] * ar[m] + ai[m] * ai[m];
                Cre[SIDX(m, m)] += pr;
#pragma unroll
                for (int k = 0; k < 6; k++) Vre[k][SIDX(m, m)] += rr[k] * pr;
            }
#pragma unroll
            for (int n = m + 1; n < 6; n++) {
                // p = x[m] * conj(x[n])
                const float pr = ar[m] * ar[n] + ai[m] * ai[n];
                const float pi = ai[m] * ar[n] - ar[m] * ai[n];
                Cre[SIDX(m, n)] += pr;
                Cim[AIDX(m, n)] += pi;
#pragma unroll
                for (int k = 0; k < 6; k++) {
                    Vre[k][SIDX(m, n)] += rr[k] * pr;
                    Vim[k][AIDX(m, n)] += rr[k] * pi;
                }
            }
        }
    }

    // butterfly reduce all 252 accumulators across the wave
#pragma unroll
    for (int k = 0; k < 6; k++) {
#pragma unroll
        for (int p = 0; p < 21; p++) {
            float v = Vre[k][p];
            v += __shfl_xor(v, 1); v += __shfl_xor(v, 2); v += __shfl_xor(v, 4);
            v += __shfl_xor(v, 8); v += __shfl_xor(v, 16); v += __shfl_xor(v, 32);
            Vre[k][p] = v;
        }
#pragma unroll
        for (int p = 0; p < 15; p++) {
            float v = Vim[k][p];
            v += __shfl_xor(v, 1); v += __shfl_xor(v, 2); v += __shfl_xor(v, 4);
            v += __shfl_xor(v, 8); v += __shfl_xor(v, 16); v += __shfl_xor(v, 32);
            Vim[k][p] = v;
        }
    }
#pragma unroll
    for (int p = 0; p < 21; p++) {
        float v = Cre[p];
        v += __shfl_xor(v, 1); v += __shfl_xor(v, 2); v += __shfl_xor(v, 4);
        v += __shfl_xor(v, 8); v += __shfl_xor(v, 16); v += __shfl_xor(v, 32);
        Cre[p] = v;
    }
#pragma unroll
    for (int p = 0; p < 15; p++) {
        float v = Cim[p];
        v += __shfl_xor(v, 1); v += __shfl_xor(v, 2); v += __shfl_xor(v, 4);
        v += __shfl_xor(v, 8); v += __shfl_xor(v, 16); v += __shfl_xor(v, 32);
        Cim[p] = v;
    }

    if (lane == 0) {
        const float invT = 1.0f / (float)TQ;
        float2* Vp = reinterpret_cast<float2*>(V + (size_t)bf * 432);
#pragma unroll
        for (int k = 0; k < 6; k++)
#pragma unroll
            for (int m = 0; m < 6; m++)
#pragma unroll
                for (int n = 0; n < 6; n++) {
                    float re, im;
                    if (m <= n) {
                        re = Vre[k][SIDX(m, n)];
                        im = (m == n) ? 0.0f : Vim[k][AIDX(m, n)];
                    } else {
                        re = Vre[k][SIDX(n, m)];
                        im = -Vim[k][AIDX(n, m)];
                    }
                    re *= invT; im *= invT;
                    if (m == n) re += 1e-6f;   // + EPS * I (after /T, as in reference)
                    Vp[(k * 6 + m) * 6 + n] = make_float2(re, im);
                }
        float2* Cp = reinterpret_cast<float2*>(Cw + (size_t)bf * 72);
#pragma unroll
        for (int m = 0; m < 6; m++)
#pragma unroll
            for (int n = 0; n < 6; n++) {
                float re, im;
                if (m <= n) {
                    re = Cre[SIDX(m, n)];
                    im = (m == n) ? 0.0f : Cim[AIDX(m, n)];
                } else {
                    re = Cre[SIDX(n, m)];
                    im = -Cim[AIDX(n, m)];
                }
                Cp[m * 6 + n] = make_float2(re, im);
            }
    }
}

// ---------------------------------------------------------------------------
// K2: one ISS iteration (6 sequential k-steps) + trace(Q C Q^H) partial for
// the per-batch scale. 8 lanes per (b,f): lane kp<6 owns row kp of Q and
// V[kp]; pivot row q broadcast via width-8 shuffles.
// Sprev == nullptr for iteration 1; else Q is pre-divided by sqrt(clip(scale)).
// ---------------------------------------------------------------------------
__global__ __launch_bounds__(256) void k_iter(
    const float* __restrict__ V, const float* __restrict__ Cw,
    const float* __restrict__ Qre_in, const float* __restrict__ Qim_in,
    const float* __restrict__ Sprev,
    float* __restrict__ Qre_out, float* __restrict__ Qim_out,
    float* __restrict__ Sout)
{
    const int gid = blockIdx.x * 256 + threadIdx.x;
    const int g   = gid >> 3;          // (b,f) index
    const int kp  = gid & 7;           // row owned (6,7 inactive dupes of 5)
    if (g >= BFQ) return;
    const int b  = g / FQ;
    const int kk = kp < 6 ? kp : 5;

    // V[kk] (6x6 complex) and C (6x6 complex), full matrices
    float Vr[36], Vi[36], Cr[36], Ci[36];
    const float2* Vp = reinterpret_cast<const float2*>(V) + (size_t)g * 216 + kk * 36;
    const float2* Cp = reinterpret_cast<const float2*>(Cw) + (size_t)g * 36;
#pragma unroll
    for (int e = 0; e < 36; e++) { float2 v = Vp[e]; Vr[e] = v.x; Vi[e] = v.y; }
#pragma unroll
    for (int e = 0; e < 36; e++) { float2 v = Cp[e]; Cr[e] = v.x; Ci[e] = v.y; }

    float Qr[6], Qi[6];
    const float* qrp = Qre_in + (size_t)g * 36 + kk * 6;
    const float* qip = Qim_in + (size_t)g * 36 + kk * 6;
#pragma unroll
    for (int m = 0; m < 6; m++) { Qr[m] = qrp[m]; Qi[m] = qip[m]; }

    if (Sprev) {
        const float sc = Sprev[b] * (1.0f / (float)FMTQ);
        const float s  = rsqrtf(fmaxf(sc, 1e-6f));
#pragma unroll
        for (int m = 0; m < 6; m++) { Qr[m] *= s; Qi[m] *= s; }
    }

#pragma unroll
    for (int k = 0; k < 6; k++) {
        // q = current row k (pre-update copy), broadcast from lane k
        float qr[6], qi[6];
#pragma unroll
        for (int m = 0; m < 6; m++) {
            qr[m] = __shfl(Qr[m], k, 8);
            qi[m] = __shfl(Qi[m], k, 8);
        }
        // W[m] = sum_n V[kk][m][n] * conj(q[n])
        float Wr[6], Wi[6];
#pragma unroll
        for (int m = 0; m < 6; m++) {
            float wr = 0.0f, wi = 0.0f;
#pragma unroll
            for (int n = 0; n < 6; n++) {
                const float vr = Vr[m * 6 + n], vi = Vi[m * 6 + n];
                wr += vr * qr[n] + vi * qi[n];
                wi += vi * qr[n] - vr * qi[n];
            }
            Wr[m] = wr; Wi[m] = wi;
        }
        // qVq = Re( sum_m q[m] * W[m] ), clipped
        float qVq = 0.0f;
#pragma unroll
        for (int m = 0; m < 6; m++) qVq += qr[m] * Wr[m] - qi[m] * Wi[m];
        qVq = fmaxf(qVq, 1e-6f);

        float vr, vi;
        if (kp == k) {
            vr = 1.0f - rsqrtf(qVq);    // v[k] = 1 - qVq^(-1/2)
            vi = 0.0f;
        } else {
            float nr = 0.0f, ni = 0.0f;
#pragma unroll
            for (int m = 0; m < 6; m++) {
                nr += Qr[m] * Wr[m] - Qi[m] * Wi[m];
                ni += Qr[m] * Wi[m] + Qi[m] * Wr[m];
            }
            const float inv = 1.0f / qVq;
            vr = nr * inv; vi = ni * inv;
        }
        // row update: Q[kp][m] -= v * q[m]
#pragma unroll
        for (int m = 0; m < 6; m++) {
            Qr[m] -= vr * qr[m] - vi * qi[m];
            Qi[m] -= vr * qi[m] + vi * qr[m];
        }
    }

    // trace partial: row kk contribution to sum_m Q_m C Q_m^H  (= sum_{m,t}|Qx|^2)
    float trr = 0.0f;
#pragma unroll
    for (int m = 0; m < 6; m++) {
        float wr = 0.0f, wi = 0.0f;
#pragma unroll
        for (int n = 0; n < 6; n++) {
            const float cr = Cr[m * 6 + n], ci = Ci[m * 6 + n];
            wr += cr * Qr[n] + ci * Qi[n];     // C[m][n] * conj(Q[n])
            wi += ci * Qr[n] - cr * Qi[n];
        }
        trr += Qr[m] * wr - Qi[m] * wi;        // Re( Q[m] * w[m] )
    }
    if (kp >= 6) trr = 0.0f;
    trr += __shfl_xor(trr, 1, 8);
    trr += __shfl_xor(trr, 2, 8);
    trr += __shfl_xor(trr, 4, 8);
    if (kp == 0) atomicAdd(&Sout[b], trr);

    if (kp < 6) {
        float* qro = Qre_out + (size_t)g * 36 + kp * 6;
        float* qio = Qim_out + (size_t)g * 36 + kp * 6;
#pragma unroll
        for (int m = 0; m < 6; m++) { qro[m] = Qr[m]; qio[m] = Qi[m]; }
    }
}

// ---------------------------------------------------------------------------
// K3a: Q_final = Q2 / sqrt(clip(scale2,1e-6)), written PLANAR:
//   out_re[idx] at outQre, out_im[idx] at outQim (outQim may be null: real-only)
// ---------------------------------------------------------------------------
__global__ __launch_bounds__(256) void k_qout(
    const float* __restrict__ Q2r, const float* __restrict__ Q2i,
    const float* __restrict__ S2, float* __restrict__ outQre,
    float* __restrict__ outQim)
{
    const int idx = blockIdx.x * 256 + threadIdx.x;
    if (idx >= BFQ * 36) return;
    const int bf = idx / 36;
    const int b  = bf / FQ;
    const float sc = S2[b] * (1.0f / (float)FMTQ);
    const float s  = rsqrtf(fmaxf(sc, 1e-6f));
    outQre[idx] = Q2r[idx] * s;
    if (outQim) outQim[idx] = Q2i[idx] * s;
}

// ---------------------------------------------------------------------------
// K3b: xt[m,t] = |Q2 x|^2 / scale2   (raw scale2, matching reference)
// One 256-thread block per (b,f); threads stride t.
// ---------------------------------------------------------------------------
__global__ __launch_bounds__(256) void k_xt(
    const float* __restrict__ xre, const float* __restrict__ xim,
    const float* __restrict__ Q2r, const float* __restrict__ Q2i,
    const float* __restrict__ S2, float* __restrict__ out)
{
    const int bf = blockIdx.x;
    const int b  = bf / FQ;
    float Qr[36], Qi[36];
    const float* qrp = Q2r + (size_t)bf * 36;
    const float* qip = Q2i + (size_t)bf * 36;
#pragma unroll
    for (int e = 0; e < 36; e++) { Qr[e] = qrp[e]; Qi[e] = qip[e]; }
    const float inv_scale = (float)FMTQ / S2[b];

    const float* xr = xre + (size_t)bf * MQ * TQ;
    const float* xi = xim + (size_t)bf * MQ * TQ;
    float* op = out + (size_t)bf * MQ * TQ;

    for (int t = threadIdx.x; t < TQ; t += 256) {
        float ar[6], ai[6];
#pragma unroll
        for (int n = 0; n < 6; n++) { ar[n] = xr[n * TQ + t]; ai[n] = xi[n * TQ + t]; }
#pragma unroll
        for (int m = 0; m < 6; m++) {
            float cr = 0.0f, ci = 0.0f;
#pragma unroll
            for (int n = 0; n < 6; n++) {
                const float wr = Qr[m * 6 + n], wi = Qi[m * 6 + n];
                cr += wr * ar[n] - wi * ai[n];
                ci += wr * ai[n] + wi * ar[n];
            }
            op[m * TQ + t] = (cr * cr + ci * ci) * inv_scale;
        }
    }
}

// ---------------------------------------------------------------------------
extern "C" void kernel_launch(void* const* d_in, const int* in_sizes, int n_in,
                              void* d_out, int out_size, void* d_ws, size_t ws_size,
                              hipStream_t stream)
{
    (void)in_sizes; (void)n_in; (void)ws_size;
    const float* r   = (const float*)d_in[0];
    const float* Qre = (const float*)d_in[1];
    const float* Qim = (const float*)d_in[2];
    const float* xre = (const float*)d_in[3];
    const float* xim = (const float*)d_in[4];

    // workspace layout (floats): V | C | Q1r | Q1i | Q2r | Q2i | S1[16] | S2[16]
    float* ws  = (float*)d_ws;
    float* V   = ws;                          // BFQ*432
    float* Cw  = V   + (size_t)BFQ * 432;     // BFQ*72
    float* Q1r = Cw  + (size_t)BFQ * 72;      // BFQ*36
    float* Q1i = Q1r + (size_t)BFQ * 36;
    float* Q2r = Q1i + (size_t)BFQ * 36;
    float* Q2i = Q2r + (size_t)BFQ * 36;
    float* S1  = Q2i + (size_t)BFQ * 36;      // 16
    float* S2  = S1 + 16;                     // 16

    // Output layout (PLANAR hypothesis): [Q_re plane | Q_im plane | xt]
    // Use out_size to detect real-only-Q variant (q_elems == BFQ*36).
    const long long xt_elems = (long long)BFQ * MQ * TQ;        // 24,672,000
    const long long q_elems  = (long long)out_size - xt_elems;  // 296,064 or 148,032
    float* out_qre = (float*)d_out;
    float* out_qim = (q_elems >= 2LL * BFQ * 36) ? out_qre + (size_t)BFQ * 36 : nullptr;
    float* out_xt  = out_qre + (size_t)(q_elems > 0 ? q_elems : 2LL * BFQ * 36);

    k_zero<<<1, 64, 0, stream>>>(S1);  // zeros S1 and S2 (contiguous 32 floats)
    k_stats<<<BFQ, 64, 0, stream>>>(r, xre, xim, V, Cw);
    const int iterGrid = (BFQ * 8 + 255) / 256;
    k_iter<<<iterGrid, 256, 0, stream>>>(V, Cw, Qre, Qim, nullptr, Q1r, Q1i, S1);
    k_iter<<<iterGrid, 256, 0, stream>>>(V, Cw, Q1r, Q1i, S1, Q2r, Q2i, S2);
    k_qout<<<(BFQ * 36 + 255) / 256, 256, 0, stream>>>(Q2r, Q2i, S2, out_qre, out_qim);
    k_xt<<<BFQ, 256, 0, stream>>>(xre, xim, Q2r, Q2i, S2, out_xt);
}

// Round 3
// 506.521 us; speedup vs baseline: 1.2932x; 1.2932x over previous
//
#include <hip/hip_runtime.h>

// Problem constants (from reference): B=16, F=257, M=6, T=1000, N_ITER=2
#define BQ 16
#define FQ 257
#define MQ 6
#define TQ 1000
#define BFQ (BQ * FQ)            // 4112 independent (b,f) problems
#define FMTQ (FQ * MQ * TQ)      // 1,542,000  (divisor for per-batch scale mean)

// ---------------------------------------------------------------------------
// K0: zero the 32 scale accumulators (S1[16], S2[16] contiguous)
// ---------------------------------------------------------------------------
__global__ void k_zero(float* __restrict__ S) {
    if (threadIdx.x < 32) S[threadIdx.x] = 0.0f;
}

__device__ __forceinline__ float wave_sum(float v) {
    v += __shfl_xor(v, 1);  v += __shfl_xor(v, 2);  v += __shfl_xor(v, 4);
    v += __shfl_xor(v, 8);  v += __shfl_xor(v, 16); v += __shfl_xor(v, 32);
    return v;
}

// ---------------------------------------------------------------------------
// K1: per (b,f):
//   V[k][m][n] = (1/T) sum_t r[k,t] * x[m,t] * conj(x[n,t])  + eps on diagonal
//   C[m][n]    =        sum_t x[m,t] * conj(x[n,t])   (for trace-based scale)
// 4 waves per (b,f); the 21 Hermitian (m<=n) pairs are partitioned across the
// waves at COMPILE TIME so each wave holds <=70 accumulators (no spill, vs 252
// in the 1-wave version that hit the 256-VGPR cap at 9.9% occupancy).
// Waves write disjoint V/C entries -> no cross-wave reduction needed.
// ---------------------------------------------------------------------------
template<int W> struct PL;
template<> struct PL<0> { static constexpr int np = 6;
    static constexpr int pm[6] = {0,0,0,1,1,2};
    static constexpr int pn[6] = {0,1,2,1,2,2}; };   // rows {0,1,2}
template<> struct PL<1> { static constexpr int np = 6;
    static constexpr int pm[6] = {3,3,3,4,4,5};
    static constexpr int pn[6] = {3,4,5,4,5,5}; };   // rows {3,4,5}
template<> struct PL<2> { static constexpr int np = 5;
    static constexpr int pm[6] = {0,0,0,1,1,0};
    static constexpr int pn[6] = {3,4,5,3,4,0}; };   // cross, part 1
template<> struct PL<3> { static constexpr int np = 4;
    static constexpr int pm[6] = {1,2,2,2,0,0};
    static constexpr int pn[6] = {5,3,4,5,0,0}; };   // cross, part 2

template<int W> __device__ constexpr unsigned rowMaskFn() {
    unsigned msk = 0;
    for (int p = 0; p < PL<W>::np; p++) {
        msk |= 1u << PL<W>::pm[p];
        msk |= 1u << PL<W>::pn[p];
    }
    return msk;
}

template<int W>
__device__ __forceinline__ void stats_work(
    int bf, int lane, const float* __restrict__ rp,
    const float* __restrict__ xrp, const float* __restrict__ xip,
    float* __restrict__ V, float* __restrict__ Cw)
{
    constexpr int NP = PL<W>::np;
    constexpr unsigned rowmask = rowMaskFn<W>();

    float Vre[NP][6], Vim[NP][6], Cre[NP], Cim[NP];
#pragma unroll
    for (int p = 0; p < NP; p++) {
        Cre[p] = 0.0f; Cim[p] = 0.0f;
#pragma unroll
        for (int k = 0; k < 6; k++) { Vre[p][k] = 0.0f; Vim[p][k] = 0.0f; }
    }

#pragma unroll 2
    for (int t = lane; t < TQ; t += 64) {
        float rr[6], ar[6], ai[6];
#pragma unroll
        for (int k = 0; k < 6; k++) rr[k] = rp[k * TQ + t];
#pragma unroll
        for (int row = 0; row < 6; row++) {
            if (rowmask & (1u << row)) {           // compile-time folded
                ar[row] = xrp[row * TQ + t];
                ai[row] = xip[row * TQ + t];
            }
        }
#pragma unroll
        for (int p = 0; p < NP; p++) {
            const int m = PL<W>::pm[p], n = PL<W>::pn[p];
            if (m == n) {
                const float pr = ar[m] * ar[m] + ai[m] * ai[m];
                Cre[p] += pr;
#pragma unroll
                for (int k = 0; k < 6; k++) Vre[p][k] += rr[k] * pr;
            } else {
                const float pr = ar[m] * ar[n] + ai[m] * ai[n];
                const float pi = ai[m] * ar[n] - ar[m] * ai[n];
                Cre[p] += pr;  Cim[p] += pi;
#pragma unroll
                for (int k = 0; k < 6; k++) {
                    Vre[p][k] += rr[k] * pr;
                    Vim[p][k] += rr[k] * pi;
                }
            }
        }
    }

    // butterfly-reduce this wave's accumulators
#pragma unroll
    for (int p = 0; p < NP; p++) {
        const int m = PL<W>::pm[p], n = PL<W>::pn[p];
        Cre[p] = wave_sum(Cre[p]);
        if (m != n) Cim[p] = wave_sum(Cim[p]);
#pragma unroll
        for (int k = 0; k < 6; k++) {
            Vre[p][k] = wave_sum(Vre[p][k]);
            if (m != n) Vim[p][k] = wave_sum(Vim[p][k]);
        }
    }

    if (lane == 0) {
        const float invT = 1.0f / (float)TQ;
        float2* Vg = reinterpret_cast<float2*>(V + (size_t)bf * 432);
        float2* Cg = reinterpret_cast<float2*>(Cw + (size_t)bf * 72);
#pragma unroll
        for (int p = 0; p < NP; p++) {
            const int m = PL<W>::pm[p], n = PL<W>::pn[p];
            if (m == n) {
#pragma unroll
                for (int k = 0; k < 6; k++)
                    Vg[k * 36 + m * 6 + m] = make_float2(Vre[p][k] * invT + 1e-6f, 0.0f);
                Cg[m * 6 + m] = make_float2(Cre[p], 0.0f);
            } else {
#pragma unroll
                for (int k = 0; k < 6; k++) {
                    const float re = Vre[p][k] * invT, im = Vim[p][k] * invT;
                    Vg[k * 36 + m * 6 + n] = make_float2(re,  im);
                    Vg[k * 36 + n * 6 + m] = make_float2(re, -im);
                }
                Cg[m * 6 + n] = make_float2(Cre[p],  Cim[p]);
                Cg[n * 6 + m] = make_float2(Cre[p], -Cim[p]);
            }
        }
    }
}

__global__ __launch_bounds__(256) void k_stats(
    const float* __restrict__ r, const float* __restrict__ xre,
    const float* __restrict__ xim, float* __restrict__ V, float* __restrict__ Cw)
{
    const int bf   = blockIdx.x;
    const int w    = threadIdx.x >> 6;
    const int lane = threadIdx.x & 63;
    const float* rp  = r   + (size_t)bf * MQ * TQ;
    const float* xrp = xre + (size_t)bf * MQ * TQ;
    const float* xip = xim + (size_t)bf * MQ * TQ;
    switch (w) {
        case 0:  stats_work<0>(bf, lane, rp, xrp, xip, V, Cw); break;
        case 1:  stats_work<1>(bf, lane, rp, xrp, xip, V, Cw); break;
        case 2:  stats_work<2>(bf, lane, rp, xrp, xip, V, Cw); break;
        default: stats_work<3>(bf, lane, rp, xrp, xip, V, Cw); break;
    }
}

// ---------------------------------------------------------------------------
// K2: one ISS iteration (6 sequential k-steps) + trace(Q C Q^H) partial for
// the per-batch scale. 8 lanes per (b,f): lane kp<6 owns row kp of Q and
// V[kp]; pivot row q broadcast via width-8 shuffles.
// V/C loaded as batched independent float4 (36 loads, one wait).
// ---------------------------------------------------------------------------
__global__ __launch_bounds__(256) void k_iter(
    const float* __restrict__ V, const float* __restrict__ Cw,
    const float* __restrict__ Qre_in, const float* __restrict__ Qim_in,
    const float* __restrict__ Sprev,
    float* __restrict__ Qre_out, float* __restrict__ Qim_out,
    float* __restrict__ Sout)
{
    const int gid = blockIdx.x * 256 + threadIdx.x;
    const int g   = gid >> 3;          // (b,f) index
    const int kp  = gid & 7;           // row owned (6,7 inactive dupes of 5)
    if (g >= BFQ) return;
    const int b  = g / FQ;
    const int kk = kp < 6 ? kp : 5;

    // V[kk] (6x6 complex) and C (6x6 complex): 18+18 independent float4 loads
    const float4* Vp4 = reinterpret_cast<const float4*>(V + (size_t)g * 432 + (size_t)kk * 72);
    const float4* Cp4 = reinterpret_cast<const float4*>(Cw + (size_t)g * 72);
    float4 vb[18], cb[18];
#pragma unroll
    for (int e = 0; e < 18; e++) vb[e] = Vp4[e];
#pragma unroll
    for (int e = 0; e < 18; e++) cb[e] = Cp4[e];

    float Vr[36], Vi[36], Cr[36], Ci[36];
#pragma unroll
    for (int e = 0; e < 18; e++) {
        Vr[2*e] = vb[e].x; Vi[2*e] = vb[e].y; Vr[2*e+1] = vb[e].z; Vi[2*e+1] = vb[e].w;
        Cr[2*e] = cb[e].x; Ci[2*e] = cb[e].y; Cr[2*e+1] = cb[e].z; Ci[2*e+1] = cb[e].w;
    }

    float Qr[6], Qi[6];
    const float* qrp = Qre_in + (size_t)g * 36 + kk * 6;
    const float* qip = Qim_in + (size_t)g * 36 + kk * 6;
#pragma unroll
    for (int m = 0; m < 6; m++) { Qr[m] = qrp[m]; Qi[m] = qip[m]; }

    if (Sprev) {
        const float sc = Sprev[b] * (1.0f / (float)FMTQ);
        const float s  = rsqrtf(fmaxf(sc, 1e-6f));
#pragma unroll
        for (int m = 0; m < 6; m++) { Qr[m] *= s; Qi[m] *= s; }
    }

#pragma unroll
    for (int k = 0; k < 6; k++) {
        // q = current row k (pre-update copy), broadcast from lane k
        float qr[6], qi[6];
#pragma unroll
        for (int m = 0; m < 6; m++) {
            qr[m] = __shfl(Qr[m], k, 8);
            qi[m] = __shfl(Qi[m], k, 8);
        }
        // W[m] = sum_n V[kk][m][n] * conj(q[n])
        float Wr[6], Wi[6];
#pragma unroll
        for (int m = 0; m < 6; m++) {
            float wr = 0.0f, wi = 0.0f;
#pragma unroll
            for (int n = 0; n < 6; n++) {
                const float vr = Vr[m * 6 + n], vi = Vi[m * 6 + n];
                wr += vr * qr[n] + vi * qi[n];
                wi += vi * qr[n] - vr * qi[n];
            }
            Wr[m] = wr; Wi[m] = wi;
        }
        // qVq = Re( sum_m q[m] * W[m] ), clipped
        float qVq = 0.0f;
#pragma unroll
        for (int m = 0; m < 6; m++) qVq += qr[m] * Wr[m] - qi[m] * Wi[m];
        qVq = fmaxf(qVq, 1e-6f);

        float vr, vi;
        if (kp == k) {
            vr = 1.0f - rsqrtf(qVq);    // v[k] = 1 - qVq^(-1/2)
            vi = 0.0f;
        } else {
            float nr = 0.0f, ni = 0.0f;
#pragma unroll
            for (int m = 0; m < 6; m++) {
                nr += Qr[m] * Wr[m] - Qi[m] * Wi[m];
                ni += Qr[m] * Wi[m] + Qi[m] * Wr[m];
            }
            const float inv = 1.0f / qVq;
            vr = nr * inv; vi = ni * inv;
        }
        // row update: Q[kp][m] -= v * q[m]
#pragma unroll
        for (int m = 0; m < 6; m++) {
            Qr[m] -= vr * qr[m] - vi * qi[m];
            Qi[m] -= vr * qi[m] + vi * qr[m];
        }
    }

    // trace partial: row kk contribution to sum_m Q_m C Q_m^H  (= sum_{m,t}|Qx|^2)
    float trr = 0.0f;
#pragma unroll
    for (int m = 0; m < 6; m++) {
        float wr = 0.0f, wi = 0.0f;
#pragma unroll
        for (int n = 0; n < 6; n++) {
            const float cr = Cr[m * 6 + n], ci = Ci[m * 6 + n];
            wr += cr * Qr[n] + ci * Qi[n];     // C[m][n] * conj(Q[n])
            wi += ci * Qr[n] - cr * Qi[n];
        }
        trr += Qr[m] * wr - Qi[m] * wi;        // Re( Q[m] * w[m] )
    }
    if (kp >= 6) trr = 0.0f;
    trr += __shfl_xor(trr, 1, 8);
    trr += __shfl_xor(trr, 2, 8);
    trr += __shfl_xor(trr, 4, 8);
    if (kp == 0) atomicAdd(&Sout[b], trr);

    if (kp < 6) {
        float* qro = Qre_out + (size_t)g * 36 + kp * 6;
        float* qio = Qim_out + (size_t)g * 36 + kp * 6;
#pragma unroll
        for (int m = 0; m < 6; m++) { qro[m] = Qr[m]; qio[m] = Qi[m]; }
    }
}

// ---------------------------------------------------------------------------
// K3a: Q_final = Q2 / sqrt(clip(scale2,1e-6)), written PLANAR (re plane, im plane)
// ---------------------------------------------------------------------------
__global__ __launch_bounds__(256) void k_qout(
    const float* __restrict__ Q2r, const float* __restrict__ Q2i,
    const float* __restrict__ S2, float* __restrict__ outQre,
    float* __restrict__ outQim)
{
    const int idx = blockIdx.x * 256 + threadIdx.x;
    if (idx >= BFQ * 36) return;
    const int bf = idx / 36;
    const int b  = bf / FQ;
    const float sc = S2[b] * (1.0f / (float)FMTQ);
    const float s  = rsqrtf(fmaxf(sc, 1e-6f));
    outQre[idx] = Q2r[idx] * s;
    if (outQim) outQim[idx] = Q2i[idx] * s;
}

// ---------------------------------------------------------------------------
// K3b: xt[m,t] = |Q2 x|^2 / scale2   (raw scale2, matching reference)
// One 256-thread block per (b,f); threads stride t; Q loaded via float4.
// ---------------------------------------------------------------------------
__global__ __launch_bounds__(256) void k_xt(
    const float* __restrict__ xre, const float* __restrict__ xim,
    const float* __restrict__ Q2r, const float* __restrict__ Q2i,
    const float* __restrict__ S2, float* __restrict__ out)
{
    const int bf = blockIdx.x;
    const int b  = bf / FQ;
    const float4* qr4 = reinterpret_cast<const float4*>(Q2r + (size_t)bf * 36);
    const float4* qi4 = reinterpret_cast<const float4*>(Q2i + (size_t)bf * 36);
    float4 qrb[9], qib[9];
#pragma unroll
    for (int e = 0; e < 9; e++) qrb[e] = qr4[e];
#pragma unroll
    for (int e = 0; e < 9; e++) qib[e] = qi4[e];
    float Qr[36], Qi[36];
#pragma unroll
    for (int e = 0; e < 9; e++) {
        Qr[4*e] = qrb[e].x; Qr[4*e+1] = qrb[e].y; Qr[4*e+2] = qrb[e].z; Qr[4*e+3] = qrb[e].w;
        Qi[4*e] = qib[e].x; Qi[4*e+1] = qib[e].y; Qi[4*e+2] = qib[e].z; Qi[4*e+3] = qib[e].w;
    }
    const float inv_scale = (float)FMTQ / S2[b];

    const float* xr = xre + (size_t)bf * MQ * TQ;
    const float* xi = xim + (size_t)bf * MQ * TQ;
    float* op = out + (size_t)bf * MQ * TQ;

    for (int t = threadIdx.x; t < TQ; t += 256) {
        float ar[6], ai[6];
#pragma unroll
        for (int n = 0; n < 6; n++) { ar[n] = xr[n * TQ + t]; ai[n] = xi[n * TQ + t]; }
#pragma unroll
        for (int m = 0; m < 6; m++) {
            float cr = 0.0f, ci = 0.0f;
#pragma unroll
            for (int n = 0; n < 6; n++) {
                const float wr = Qr[m * 6 + n], wi = Qi[m * 6 + n];
                cr += wr * ar[n] - wi * ai[n];
                ci += wr * ai[n] + wi * ar[n];
            }
            op[m * TQ + t] = (cr * cr + ci * ci) * inv_scale;
        }
    }
}

// ---------------------------------------------------------------------------
extern "C" void kernel_launch(void* const* d_in, const int* in_sizes, int n_in,
                              void* d_out, int out_size, void* d_ws, size_t ws_size,
                              hipStream_t stream)
{
    (void)in_sizes; (void)n_in; (void)ws_size;
    const float* r   = (const float*)d_in[0];
    const float* Qre = (const float*)d_in[1];
    const float* Qim = (const float*)d_in[2];
    const float* xre = (const float*)d_in[3];
    const float* xim = (const float*)d_in[4];

    // workspace layout (floats): V | C | Q1r | Q1i | Q2r | Q2i | S1[16] | S2[16]
    float* ws  = (float*)d_ws;
    float* V   = ws;                          // BFQ*432
    float* Cw  = V   + (size_t)BFQ * 432;     // BFQ*72
    float* Q1r = Cw  + (size_t)BFQ * 72;      // BFQ*36
    float* Q1i = Q1r + (size_t)BFQ * 36;
    float* Q2r = Q1i + (size_t)BFQ * 36;
    float* Q2i = Q2r + (size_t)BFQ * 36;
    float* S1  = Q2i + (size_t)BFQ * 36;      // 16
    float* S2  = S1 + 16;                     // 16

    // Output layout (PLANAR, verified R2): [Q_re plane | Q_im plane | xt]
    const long long xt_elems = (long long)BFQ * MQ * TQ;        // 24,672,000
    const long long q_elems  = (long long)out_size - xt_elems;  // 296,064 or 148,032
    float* out_qre = (float*)d_out;
    float* out_qim = (q_elems >= 2LL * BFQ * 36) ? out_qre + (size_t)BFQ * 36 : nullptr;
    float* out_xt  = out_qre + (size_t)(q_elems > 0 ? q_elems : 2LL * BFQ * 36);

    k_zero<<<1, 64, 0, stream>>>(S1);  // zeros S1 and S2 (contiguous 32 floats)
    k_stats<<<BFQ, 256, 0, stream>>>(r, xre, xim, V, Cw);
    const int iterGrid = (BFQ * 8 + 255) / 256;
    k_iter<<<iterGrid, 256, 0, stream>>>(V, Cw, Qre, Qim, nullptr, Q1r, Q1i, S1);
    k_iter<<<iterGrid, 256, 0, stream>>>(V, Cw, Q1r, Q1i, S1, Q2r, Q2i, S2);
    k_qout<<<(BFQ * 36 + 255) / 256, 256, 0, stream>>>(Q2r, Q2i, S2, out_qre, out_qim);
    k_xt<<<BFQ, 256, 0, stream>>>(xre, xim, Q2r, Q2i, S2, out_xt);
}